// Round 19
// baseline (968.725 us; speedup 1.0000x reference)
//
#include <hip/hip_runtime.h>
#include <math.h>

#define NB 16
#define NE 4
#define THRESH 0.2f
#define LIN_NS 64

typedef __attribute__((ext_vector_type(8))) _Float16 f16x8;
typedef __attribute__((ext_vector_type(4))) float f32x4;
typedef unsigned short u16;
typedef unsigned int u32;

__device__ inline u16 f16bits(float v) { _Float16 h = (_Float16)v; return __builtin_bit_cast(u16, h); }

// ---------------- repack: expert weights (main+pos) and fin weights to single fp16 ----------------
// Wm: [ij][m=e*CO+co][CINp]   Wp: [m][64]   fW: [o][CO]
// CIN==3 (L1): Wp holds the UNIFIED K=64 weights (27 main + 36 pos).
__global__ void repack_all_kernel(const float* __restrict__ ew, const float* __restrict__ fw,
    u16* __restrict__ Wm, u16* __restrict__ Wp, u16* __restrict__ fW,
    int CO, int CIN, int CINp, int C) {
    const int M = NE * CO;
    const int n1 = 9 * M * CINp, n2 = M * 64, n3 = CO * CO;
    const int n = n1 + n2 + n3;
    for (int i = blockIdx.x * blockDim.x + threadIdx.x; i < n; i += gridDim.x * blockDim.x) {
        if (i < n1) {
            int k = i % CINp; int t = i / CINp; int m = t % M; int ij = t / M;
            float v = (k < CIN) ? ew[(m * C + k) * 9 + ij] : 0.f;
            Wm[i] = f16bits(v);
        } else if (i < n1 + n2) {
            int j = i - n1; int kp = j & 63; int m = j >> 6;
            float v = 0.f;
            if (CIN == 3) {
                if (kp < 27)      { int c = kp / 9,  ij = kp % 9;  v = ew[(m * C + c) * 9 + ij]; }
                else if (kp < 63) { int q = kp - 27; int pc = q / 9, ij = q % 9; v = ew[(m * C + 3 + pc) * 9 + ij]; }
            } else {
                if (kp < 36) { int pc = kp / 9, ij = kp % 9; v = ew[(m * C + CIN + pc) * 9 + ij]; }
            }
            Wp[j] = f16bits(v);
        } else {
            int j = i - n1 - n2;
            fW[j] = f16bits(fw[j]);
        }
    }
}

// ---------------- router: pooled conv -> softmax scores (verified; NO atomics) ----------------
template<int CIN, int C>
__global__ __launch_bounds__(256) void router_kernel(
    const float* __restrict__ X, const float* __restrict__ pw, const float* __restrict__ pb,
    const float* __restrict__ rw, const float* __restrict__ rb,
    float* __restrict__ scores, int H, int W, int nP)
{
    __shared__ float S[4][C * 9 + 8];
    const int wv = threadIdx.x >> 6;
    const int lane = threadIdx.x & 63;
    const int bp = blockIdx.x * 4 + wv;
    const int P = nP * nP;
    const int b = bp / P, pi = bp % P;
    const int py = pi / nP, px = pi % nP;
    const int h = lane >> 3, w = lane & 7;
    const int gy = py * 8 + h, gx = px * 8 + w;
    float* Sw = S[wv];
    for (int c = 0; c < C; ++c) {
        float v;
        if (c < CIN) {
            v = X[(((size_t)b * CIN + c) * H + gy) * W + gx];
        } else {
            float t = (c == CIN || c == CIN + 2) ? gx * (1.f / (W - 1)) : gy * (1.f / (H - 1));
            v = (c >= CIN + 2) ? sinf(3.14159265358979323846f * t) : t;
        }
        float r = v;
        r += __shfl_xor(r, 1); r += __shfl_xor(r, 2); r += __shfl_xor(r, 4);
        float cc = v;
        cc += __shfl_xor(cc, 8); cc += __shfl_xor(cc, 16); cc += __shfl_xor(cc, 32);
        float T = r;
        T += __shfl_xor(T, 8); T += __shfl_xor(T, 16); T += __shfl_xor(T, 32);
        float R0 = __shfl(r, 0), R7 = __shfl(r, 56);
        float C0 = __shfl(cc, 0), C7 = __shfl(cc, 7);
        float x00 = __shfl(v, 0), x07 = __shfl(v, 7);
        float x70 = __shfl(v, 56), x77 = __shfl(v, 63);
        if (lane < 9) {
            int i = lane / 3, j = lane % 3;
            float s = T;
            if (i == 0) s -= R7; else if (i == 2) s -= R0;
            if (j == 0) s -= C7; else if (j == 2) s -= C0;
            if (i == 0 && j == 0) s += x77;
            else if (i == 0 && j == 2) s += x70;
            else if (i == 2 && j == 0) s += x07;
            else if (i == 2 && j == 2) s += x00;
            Sw[c * 9 + lane] = s;
        }
    }
    __syncthreads();
    if (lane < 8) {
        const int o = lane;
        float acc = 0.f;
        for (int c = 0; c < C; ++c) {
            #pragma unroll
            for (int ij = 0; ij < 9; ++ij)
                acc += pw[(o * C + c) * 9 + ij] * Sw[c * 9 + ij];
        }
        Sw[C * 9 + o] = acc * (1.f / 64.f) + pb[o];
    }
    __syncthreads();
    if (lane == 0) {
        float lg[NE];
        float m = -1e30f;
        #pragma unroll
        for (int e = 0; e < NE; ++e) {
            float a = rb[e];
            #pragma unroll
            for (int o = 0; o < 8; ++o) a += Sw[C * 9 + o] * rw[e * 8 + o];
            lg[e] = a;
            m = fmaxf(m, a);
        }
        float ssum = 0.f;
        #pragma unroll
        for (int e = 0; e < NE; ++e) { lg[e] = __expf(lg[e] - m); ssum += lg[e]; }
        float inv = 1.f / ssum;
        #pragma unroll
        for (int e = 0; e < NE; ++e) scores[bp * NE + e] = lg[e] * inv;
    }
}

// ---------------- border: Xn border pixels = fin bias ----------------
__global__ __launch_bounds__(256) void border_kernel(float* __restrict__ Xn,
                                                     const float* __restrict__ fb,
                                                     int CO, int H, int W)
{
    const int Hout = H + 8, Wout = W + 8;
    const int nb = 16 * H + 64;
    const long total = (long)NB * CO * nb;
    for (long i = (long)blockIdx.x * blockDim.x + threadIdx.x; i < total;
         i += (long)gridDim.x * blockDim.x) {
        int j = (int)(i % nb); long t = i / nb; int o = (int)(t % CO); int b = (int)(t / CO);
        int y, x;
        if (j < 4 * Wout)       { y = j / Wout;             x = j % Wout; }
        else if (j < 8 * Wout)  { int j2 = j - 4 * Wout; y = H + 4 + j2 / Wout; x = j2 % Wout; }
        else                    { int j3 = j - 8 * Wout; y = 4 + j3 / 8;
                                  int c8 = j3 % 8; x = (c8 < 4) ? c8 : W + 4 + (c8 - 4); }
        Xn[(((size_t)b * CO + o) * Hout + y) * Wout + x] = fb[o];
    }
}

// ---------------- fused expert + fin, 2 patches per block ----------------
// R19: FAT layers -> 1024-thread blocks (16 waves). Each wave owns 4 N-tiles of ONE
// patch (gW = wv>>3) x 16-co x 4 experts: acc[4][4] = 64 AGPR, epilogue wave-local
// (one patch's scores, no pass-carry, no cross-wave reduce -- avoids R12-R14 spill
// modes). Simple (non-pipelined) A loop: at 4 waves/SIMD TLP hides L2 latency (the
// R17 SW pipeline was compensation for 2-wave occupancy). Same weight amortization
// (block still streams Wm once / 2 patches). THIN/UNI keep the proven 512 R17 path.
template<int CIN, int CINp, int CO>
__global__ __launch_bounds__((CO == 128 ? 1024 : 512), (CO == 128 ? 4 : 2))
void expert_fused_kernel(
    const float* __restrict__ X,
    const u16* __restrict__ Wm, const u16* __restrict__ Wp, const u16* __restrict__ fW,
    const float* __restrict__ eb, const float* __restrict__ fb,
    const float* __restrict__ scores, int BPtot,
    float* __restrict__ Xn, int H, int W, int nP)
{
    constexpr int M = NE * CO;
    constexpr int KSM = CINp / 32;
    constexpr int LOGK = (KSM == 4) ? 2 : (KSM == 2 ? 1 : 0);
    constexpr int NS = 9 * KSM;
    constexpr int SP = CINp + 8;
    constexpr int PIP = 72;
    constexpr int CP = CO + 8;
    constexpr bool FAT = (CO == 128);
    constexpr bool UNI = (CIN == 3);
    constexpr int TPB = FAT ? 1024 : 512;
    constexpr int WVS = TPB / 64;
    constexpr int NT = 4;
    constexpr int PATW = 2 * 100 * SP;
    constexpr int POSW = 2 * 64 * PIP;
    constexpr int COMBW = 2 * 64 * CP;
    constexpr int SMW = (PATW + POSW > COMBW) ? (PATW + POSW) : COMBW;

    __shared__ __align__(16) u16 smem[SMW];
    __shared__ float pospix[2][4][64];
    __shared__ float xpix[2][3][64];   // UNI only
    __shared__ float gsh[WVS][NE];
    u16* pat = smem;
    u16* posim = smem + PATW;
    u16* comb = smem;              // aliases pat/posim; valid after the post-GEMM barrier

    const int P = nP * nP;
    const int bp0 = blockIdx.x * 2, bp1 = bp0 + 1;
    const int b0 = bp0 / P, pi0 = bp0 % P, py0 = pi0 / nP, px0 = pi0 % nP;
    const int b1 = bp1 / P, pi1 = bp1 % P, py1 = pi1 / nP, px1 = pi1 % nP;
    const int tid = threadIdx.x;
    const int Hout = H + 8, Wout = W + 8;

    // ---- phase A: zero pat (non-UNI), pospix, xpix (UNI), gate partial scan ----
    if constexpr (!UNI) {
        for (int i = tid; i < 100 * SP; i += TPB) ((u32*)pat)[i] = 0;
    }
    {
        int g = (tid >> 8) & 1, r = tid & 255, pc = r >> 6, p = r & 63;
        int gy = (g ? py1 : py0) * 8 + (p >> 3), gx = (g ? px1 : px0) * 8 + (p & 7);
        float t = (pc == 0 || pc == 2) ? gx * (1.f / (W - 1)) : gy * (1.f / (H - 1));
        pospix[g][pc][p] = (pc >= 2) ? sinf(3.14159265358979323846f * t) : t;  // dup writes (TPB>512) benign
    }
    if constexpr (UNI) {
        for (int i = tid; i < 2 * 3 * 64; i += TPB) {
            int g = i / 192, r = i % 192, c = r >> 6, p = r & 63;
            int bb = g ? b1 : b0, py = g ? py1 : py0, px = g ? px1 : px0;
            xpix[g][c][p] = X[(((size_t)bb * CIN + c) * H + py * 8 + (p >> 3)) * W + px * 8 + (p & 7)];
        }
    }
    float gm[NE] = {-1e30f, -1e30f, -1e30f, -1e30f};
    for (int i = tid; i < BPtot; i += TPB) {
        float4 sc = ((const float4*)scores)[i];
        gm[0] = fmaxf(gm[0], sc.x); gm[1] = fmaxf(gm[1], sc.y);
        gm[2] = fmaxf(gm[2], sc.z); gm[3] = fmaxf(gm[3], sc.w);
    }
    __syncthreads();

    // ---- phase B: fill pat (non-UNI), build posim, gate wave-reduce ----
    if constexpr (!UNI) {
        for (int i = tid; i < 2 * CIN * 16; i += TPB) {
            int g = i / (CIN * 16), j = i % (CIN * 16);
            int c = j >> 4, q = j & 15, h = q >> 1, w4 = (q & 1) * 4;
            int bb = g ? b1 : b0, py = g ? py1 : py0, px = g ? px1 : px0;
            const float4 v = *(const float4*)&X[(((size_t)bb * CIN + c) * H + py * 8 + h) * W + px * 8 + w4];
            int base = g * 100 * SP + c;
            pat[base + ((h + 1) * 10 + (w4 + 1)) * SP] = f16bits(v.x);
            pat[base + ((h + 1) * 10 + (w4 + 2)) * SP] = f16bits(v.y);
            pat[base + ((h + 1) * 10 + (w4 + 3)) * SP] = f16bits(v.z);
            pat[base + ((h + 1) * 10 + (w4 + 4)) * SP] = f16bits(v.w);
        }
    }
    for (int i = tid; i < 2 * 64 * 64; i += TPB) {
        int g = i >> 12, r = i & 4095, pix = r >> 6, kp = r & 63;
        float v = 0.f;
        if constexpr (UNI) {
            if (kp < 27) {
                int c = kp / 9, ij = kp % 9;
                int hh = (pix >> 3) + ij / 3 - 1, ww = (pix & 7) + ij % 3 - 1;
                if (hh >= 0 && hh < 8 && ww >= 0 && ww < 8) v = xpix[g][c][hh * 8 + ww];
            } else if (kp < 63) {
                int q = kp - 27; int pc = q / 9, ij = q % 9;
                int hh = (pix >> 3) + ij / 3 - 1, ww = (pix & 7) + ij % 3 - 1;
                if (hh >= 0 && hh < 8 && ww >= 0 && ww < 8) v = pospix[g][pc][hh * 8 + ww];
            }
        } else {
            if (kp < 36) {
                int pc = kp / 9, ij = kp % 9;
                int hh = (pix >> 3) + ij / 3 - 1, ww = (pix & 7) + ij % 3 - 1;
                if (hh >= 0 && hh < 8 && ww >= 0 && ww < 8) v = pospix[g][pc][hh * 8 + ww];
            }
        }
        posim[g * 64 * PIP + pix * PIP + kp] = f16bits(v);
    }
    {
        const int lane = tid & 63, wvi = tid >> 6;
        #pragma unroll
        for (int e = 0; e < NE; ++e) {
            float v = gm[e];
            for (int o = 32; o; o >>= 1) v = fmaxf(v, __shfl_xor(v, o));
            gm[e] = v;
        }
        if (lane == 0) {
            #pragma unroll
            for (int e = 0; e < NE; ++e) gsh[wvi][e] = gm[e];
        }
    }
    __syncthreads();

    const int lane = tid & 63, wv = tid >> 6;
    const int colp = lane & 15, kg = lane >> 4;
    const int co0 = FAT ? (wv & 7) * 16 : (wv & 3) * 16;
    const int gW  = FAT ? (wv >> 3)     : (wv >> 2);
    const int bpg = gW ? bp1 : bp0;

    int prow[NT];
    #pragma unroll
    for (int nt = 0; nt < NT; ++nt) {
        int pix = nt * 16 + colp;
        prow[nt] = gW * 100 * SP + ((pix >> 3) * 10 + (pix & 7)) * SP;
    }
    int aoff[NE];
    #pragma unroll
    for (int e = 0; e < NE; ++e)
        aoff[e] = (e * CO + co0 + colp) * CINp + kg * 8;

    f32x4 acc[NE][NT];
    #pragma unroll
    for (int e = 0; e < NE; ++e)
        #pragma unroll
        for (int nt = 0; nt < NT; ++nt) acc[e][nt] = (f32x4){0.f, 0.f, 0.f, 0.f};

    if constexpr (!UNI && FAT) {
        // simple loop: TLP (4 waves/SIMD) hides the A-load latency
        for (int s = 0; s < NS; ++s) {
            int ij = s >> LOGK, ks = s & (KSM - 1);
            const u16* Ws = Wm + (size_t)(ij * M) * CINp + ks * 32;
            f16x8 Ah[NE];
            #pragma unroll
            for (int e = 0; e < NE; ++e) Ah[e] = *(const f16x8*)(Ws + aoff[e]);
            int i3 = ij / 3;
            int tb = (i3 * 10 + (ij - 3 * i3)) * SP + ks * 32 + kg * 8;
            #pragma unroll
            for (int nt = 0; nt < NT; ++nt) {
                f16x8 Bv = *(const f16x8*)&pat[prow[nt] + tb];
                __builtin_amdgcn_s_setprio(1);
                #pragma unroll
                for (int e = 0; e < NE; ++e)
                    acc[e][nt] = __builtin_amdgcn_mfma_f32_16x16x32_f16(Ah[e], Bv, acc[e][nt], 0, 0, 0);
                __builtin_amdgcn_s_setprio(0);
            }
        }
    } else if constexpr (!UNI) {
        // THIN: R17 depth-1 pipelined A-stream (proven at 512/2-blocks)
        f16x8 A0[NE], A1[NE];
        auto ldA = [&](int s, f16x8* A) {
            int ij = s >> LOGK, ks = s & (KSM - 1);
            const u16* Ws = Wm + (size_t)(ij * M) * CINp + ks * 32;
            #pragma unroll
            for (int e = 0; e < NE; ++e) A[e] = *(const f16x8*)(Ws + aoff[e]);
        };
        auto doStep = [&](int s, f16x8* A) {
            int ij = s >> LOGK, ks = s & (KSM - 1);
            int i3 = ij / 3;
            int tb = (i3 * 10 + (ij - 3 * i3)) * SP + ks * 32 + kg * 8;
            #pragma unroll
            for (int nt = 0; nt < NT; ++nt) {
                f16x8 Bv = *(const f16x8*)&pat[prow[nt] + tb];
                __builtin_amdgcn_s_setprio(1);
                #pragma unroll
                for (int e = 0; e < NE; ++e)
                    acc[e][nt] = __builtin_amdgcn_mfma_f32_16x16x32_f16(A[e], Bv, acc[e][nt], 0, 0, 0);
                __builtin_amdgcn_s_setprio(0);
            }
        };
        ldA(0, A0);
        int s = 0;
        for (; s + 1 < NS; s += 2) {
            ldA(s + 1, A1);
            doStep(s, A0);
            ldA((s + 2 < NS) ? s + 2 : s + 1, A0);
            doStep(s + 1, A1);
        }
        if (s < NS) doStep(s, A0);
    }

    // ---- posim GEMM (K=64): pos-only for non-UNI, the ENTIRE conv for UNI ----
    #pragma unroll
    for (int ks = 0; ks < 2; ++ks) {
        f16x8 Ap[NE];
        #pragma unroll
        for (int e = 0; e < NE; ++e) {
            int ao = (e * CO + co0 + colp) * 64 + ks * 32 + kg * 8;
            Ap[e] = *(const f16x8*)(Wp + ao);
        }
        #pragma unroll
        for (int nt = 0; nt < NT; ++nt) {
            int pix = nt * 16 + colp;
            f16x8 Bv = *(const f16x8*)&posim[gW * 64 * PIP + pix * PIP + ks * 32 + kg * 8];
            __builtin_amdgcn_s_setprio(1);
            #pragma unroll
            for (int e = 0; e < NE; ++e)
                acc[e][nt] = __builtin_amdgcn_mfma_f32_16x16x32_f16(Ap[e], Bv, acc[e][nt], 0, 0, 0);
            __builtin_amdgcn_s_setprio(0);
        }
    }

    float sgW[NE];
    #pragma unroll
    for (int e = 0; e < NE; ++e) {
        float mx = gsh[0][e];
        #pragma unroll
        for (int w8 = 1; w8 < WVS; ++w8) mx = fmaxf(mx, gsh[w8][e]);
        float gv = (mx > THRESH) ? 1.f : 0.f;
        sgW[e] = scores[bpg * NE + e] * gv;
    }
    float ebv[NE][4];
    #pragma unroll
    for (int e = 0; e < NE; ++e)
        #pragma unroll
        for (int r = 0; r < 4; ++r) ebv[e][r] = eb[e * CO + co0 + kg * 4 + r];

    __syncthreads();   // all pat/posim reads done; comb may now overwrite the region

    #pragma unroll
    for (int nt = 0; nt < NT; ++nt) {
        int pix = nt * 16 + colp;
        u16 hv[4];
        #pragma unroll
        for (int r = 0; r < 4; ++r) {
            float cv = 0.f;
            #pragma unroll
            for (int e = 0; e < NE; ++e)
                cv += sgW[e] * fmaxf(acc[e][nt][r] + ebv[e][r], 0.f);
            hv[r] = f16bits(cv);
        }
        uint2 q;
        q.x = (u32)hv[0] | ((u32)hv[1] << 16);
        q.y = (u32)hv[2] | ((u32)hv[3] << 16);
        *(uint2*)&comb[gW * 64 * CP + pix * CP + co0 + kg * 4] = q;
    }
    __syncthreads();

    // fin GEMM: wave's 16 o-rows x its patch's 4 pix-tiles
    const int o0 = co0;
    f32x4 accF[NT];
    #pragma unroll
    for (int nt = 0; nt < NT; ++nt) accF[nt] = (f32x4){0.f, 0.f, 0.f, 0.f};
    #pragma unroll
    for (int ks = 0; ks < CO / 32; ++ks) {
        int ao = (o0 + colp) * CO + ks * 32 + kg * 8;
        f16x8 ah = *(const f16x8*)(fW + ao);
        __builtin_amdgcn_s_setprio(1);
        #pragma unroll
        for (int nt = 0; nt < NT; ++nt) {
            int pix = nt * 16 + colp;
            f16x8 bv = *(const f16x8*)&comb[gW * 64 * CP + pix * CP + ks * 32 + kg * 8];
            accF[nt] = __builtin_amdgcn_mfma_f32_16x16x32_f16(ah, bv, accF[nt], 0, 0, 0);
        }
        __builtin_amdgcn_s_setprio(0);
    }
    float fbv[4];
    #pragma unroll
    for (int r = 0; r < 4; ++r) fbv[r] = fb[o0 + kg * 4 + r];
    const int bbW = gW ? b1 : b0, pyW = gW ? py1 : py0, pxW = gW ? px1 : px0;
    #pragma unroll
    for (int nt = 0; nt < NT; ++nt) {
        int pix = nt * 16 + colp;
        int gy = pyW * 8 + (pix >> 3) + 4, gx = pxW * 8 + (pix & 7) + 4;
        #pragma unroll
        for (int r = 0; r < 4; ++r) {
            int o = o0 + kg * 4 + r;
            Xn[(((size_t)bbW * CO + o) * Hout + gy) * Wout + gx] = accF[nt][r] + fbv[r];
        }
    }
}

// ---------------- final linear: stage 1 — 4 batches per block, weights read once ----------------
__global__ __launch_bounds__(256) void linear_part_kernel(
    const float* __restrict__ Xf, const float* __restrict__ lw, float* __restrict__ part)
{
    const int feat = 128 * 96 * 96;
    const int CH = feat / LIN_NS;          // 18432
    const int s = blockIdx.x & (LIN_NS - 1);
    const int bg = blockIdx.x / LIN_NS;    // 0..3
    float acc[4][10];
    #pragma unroll
    for (int bb = 0; bb < 4; ++bb)
        #pragma unroll
        for (int o = 0; o < 10; ++o) acc[bb][o] = 0.f;
    const int n4 = CH / 4;                 // 4608
    for (int i = threadIdx.x; i < n4; i += 256) {
        float4 wv[10];
        #pragma unroll
        for (int o = 0; o < 10; ++o)
            wv[o] = *(const float4*)(lw + (size_t)o * feat + (size_t)s * CH + i * 4);
        #pragma unroll
        for (int bb = 0; bb < 4; ++bb) {
            float4 xv = *(const float4*)(Xf + (size_t)(bg * 4 + bb) * feat + (size_t)s * CH + i * 4);
            #pragma unroll
            for (int o = 0; o < 10; ++o)
                acc[bb][o] += xv.x * wv[o].x + xv.y * wv[o].y + xv.z * wv[o].z + xv.w * wv[o].w;
        }
    }
    #pragma unroll
    for (int bb = 0; bb < 4; ++bb)
        #pragma unroll
        for (int o = 0; o < 10; ++o)
            for (int m = 32; m; m >>= 1) acc[bb][o] += __shfl_xor(acc[bb][o], m);
    __shared__ float sm[4][40];
    int wvi = threadIdx.x >> 6, lane = threadIdx.x & 63;
    if (lane == 0) {
        #pragma unroll
        for (int bb = 0; bb < 4; ++bb)
            #pragma unroll
            for (int o = 0; o < 10; ++o) sm[wvi][bb * 10 + o] = acc[bb][o];
    }
    __syncthreads();
    int t = threadIdx.x;
    if (t < 40) {
        float a = sm[0][t] + sm[1][t] + sm[2][t] + sm[3][t];
        int bb = t / 10, o = t % 10;
        int b = bg * 4 + bb;
        part[(b * LIN_NS + s) * 10 + o] = a;
    }
}

// ---------------- final linear: stage 2 — reduce splits + bias (deterministic) ----------------
__global__ __launch_bounds__(256) void linear_reduce_kernel(
    const float* __restrict__ part, const float* __restrict__ lb, float* __restrict__ out)
{
    int i = threadIdx.x;
    if (i < 160) {
        int b = i / 10, o = i % 10;
        float a = lb[o];
        for (int s = 0; s < LIN_NS; ++s) a += part[(b * LIN_NS + s) * 10 + o];
        out[i] = a;
    }
}

// ---------------- host driver ----------------
template<int CIN, int CINp, int CO>
static void run_layer(const float* Xin, int H, int nP, const float* const* Lw,
                      const float* rw, const float* rb,
                      const u16* Wm, const u16* Wp, const u16* fW,
                      float* scores, float* Xn, hipStream_t stream)
{
    const int W = H;
    const int BP = NB * nP * nP;
    const float* pw = Lw[0]; const float* pb = Lw[1];
    const float* ebias = Lw[3];
    const float* fb = Lw[5];
    constexpr int TPB = (CO == 128) ? 1024 : 512;

    router_kernel<CIN, CIN + 4><<<BP / 4, 256, 0, stream>>>(Xin, pw, pb, rw, rb, scores, H, W, nP);
    border_kernel<<<2048, 256, 0, stream>>>(Xn, fb, CO, H, W);
    expert_fused_kernel<CIN, CINp, CO><<<BP / 2, TPB, 0, stream>>>(
        Xin, Wm, Wp, fW, ebias, fb, scores, BP, Xn, H, W, nP);
}

extern "C" void kernel_launch(void* const* d_in, const int* in_sizes, int n_in,
                              void* d_out, int out_size, void* d_ws, size_t ws_size,
                              hipStream_t stream)
{
    const float* X0 = (const float*)d_in[0];
    const float* L[4][6];
    for (int l = 0; l < 4; ++l)
        for (int k = 0; k < 6; ++k) L[l][k] = (const float*)d_in[1 + l * 6 + k];
    const float* rw = (const float*)d_in[25];
    const float* rb = (const float*)d_in[26];
    const float* lw = (const float*)d_in[27];
    const float* lb = (const float*)d_in[28];

    // workspace (~141.5 MB): ping-pong X buffers + per-layer fp16 weights + linear partials
    char* ws = (char*)d_ws;
    const size_t XA_B = 63438848;    // 16*128*88*88*4 (L3 out, max for A)
    const size_t XB_B = 75497472;    // 16*128*96*96*4 (L4 out, max for B)
    float* XA = (float*)(ws);
    float* XB = (float*)(ws + XA_B);
    char* wp = ws + XA_B + XB_B;
    const int cfg_CO[4]   = {64, 64, 128, 128};
    const int cfg_CINp[4] = {32, 64, 64, 128};
    u16 *Wm[4], *Wp[4], *fW[4];
    for (int l = 0; l < 4; ++l) {
        int M = NE * cfg_CO[l];
        Wm[l] = (u16*)wp;            wp += (size_t)9 * M * cfg_CINp[l] * 2;
        Wp[l] = (u16*)wp;            wp += (size_t)M * 64 * 2;
        fW[l] = (u16*)wp;            wp += (size_t)cfg_CO[l] * cfg_CO[l] * 2;
    }
    float* scores = (float*)wp;
    float* lpart = scores + 1936 * 4;  // 16*LIN_NS*10 floats

    // all repacks upfront (off the inter-layer critical path)
    const int cfg_CIN[4] = {3, 64, 64, 128};
    for (int l = 0; l < 4; ++l)
        repack_all_kernel<<<512, 256, 0, stream>>>(L[l][2], L[l][4], Wm[l], Wp[l], fW[l],
                                                   cfg_CO[l], cfg_CIN[l], cfg_CINp[l], cfg_CIN[l] + 4);

    // layer l: X (NB,CIN,H,H) -> Xn (NB,CO,H+8,H+8), ping-pong A/B
    run_layer<3,   32,  64>(X0, 64,  8, L[0], rw, rb, Wm[0], Wp[0], fW[0], scores, XA, stream);
    run_layer<64,  64,  64>(XA, 72,  9, L[1], rw, rb, Wm[1], Wp[1], fW[1], scores, XB, stream);
    run_layer<64,  64, 128>(XB, 80, 10, L[2], rw, rb, Wm[2], Wp[2], fW[2], scores, XA, stream);
    run_layer<128, 128, 128>(XA, 88, 11, L[3], rw, rb, Wm[3], Wp[3], fW[3], scores, XB, stream);

    linear_part_kernel<<<LIN_NS * (NB / 4), 256, 0, stream>>>(XB, lw, lpart);
    linear_reduce_kernel<<<1, 256, 0, stream>>>(lpart, lb, (float*)d_out);
}

// Round 21
// 811.669 us; speedup vs baseline: 1.1935x; 1.1935x over previous
//
#include <hip/hip_runtime.h>
#include <math.h>

#define NB 16
#define NE 4
#define THRESH 0.2f
#define LIN_NS 64

typedef __attribute__((ext_vector_type(8))) _Float16 f16x8;
typedef __attribute__((ext_vector_type(4))) float f32x4;
typedef unsigned short u16;
typedef unsigned int u32;

__device__ inline u16 f16bits(float v) { _Float16 h = (_Float16)v; return __builtin_bit_cast(u16, h); }

// ---------------- repack: expert weights (main+pos) and fin weights to single fp16 ----------------
// Wm: [ij][m=e*CO+co][CINp]   Wp: [m][64]   fW: [o][CO]
// CIN==3 (L1): Wp holds the UNIFIED K=64 weights (27 main + 36 pos).
__global__ void repack_all_kernel(const float* __restrict__ ew, const float* __restrict__ fw,
    u16* __restrict__ Wm, u16* __restrict__ Wp, u16* __restrict__ fW,
    int CO, int CIN, int CINp, int C) {
    const int M = NE * CO;
    const int n1 = 9 * M * CINp, n2 = M * 64, n3 = CO * CO;
    const int n = n1 + n2 + n3;
    for (int i = blockIdx.x * blockDim.x + threadIdx.x; i < n; i += gridDim.x * blockDim.x) {
        if (i < n1) {
            int k = i % CINp; int t = i / CINp; int m = t % M; int ij = t / M;
            float v = (k < CIN) ? ew[(m * C + k) * 9 + ij] : 0.f;
            Wm[i] = f16bits(v);
        } else if (i < n1 + n2) {
            int j = i - n1; int kp = j & 63; int m = j >> 6;
            float v = 0.f;
            if (CIN == 3) {
                if (kp < 27)      { int c = kp / 9,  ij = kp % 9;  v = ew[(m * C + c) * 9 + ij]; }
                else if (kp < 63) { int q = kp - 27; int pc = q / 9, ij = q % 9; v = ew[(m * C + 3 + pc) * 9 + ij]; }
            } else {
                if (kp < 36) { int pc = kp / 9, ij = kp % 9; v = ew[(m * C + CIN + pc) * 9 + ij]; }
            }
            Wp[j] = f16bits(v);
        } else {
            int j = i - n1 - n2;
            fW[j] = f16bits(fw[j]);
        }
    }
}

// ---------------- router: pooled conv -> softmax scores (verified; NO atomics) ----------------
template<int CIN, int C>
__global__ __launch_bounds__(256) void router_kernel(
    const float* __restrict__ X, const float* __restrict__ pw, const float* __restrict__ pb,
    const float* __restrict__ rw, const float* __restrict__ rb,
    float* __restrict__ scores, int H, int W, int nP)
{
    __shared__ float S[4][C * 9 + 8];
    const int wv = threadIdx.x >> 6;
    const int lane = threadIdx.x & 63;
    const int bp = blockIdx.x * 4 + wv;
    const int P = nP * nP;
    const int b = bp / P, pi = bp % P;
    const int py = pi / nP, px = pi % nP;
    const int h = lane >> 3, w = lane & 7;
    const int gy = py * 8 + h, gx = px * 8 + w;
    float* Sw = S[wv];
    for (int c = 0; c < C; ++c) {
        float v;
        if (c < CIN) {
            v = X[(((size_t)b * CIN + c) * H + gy) * W + gx];
        } else {
            float t = (c == CIN || c == CIN + 2) ? gx * (1.f / (W - 1)) : gy * (1.f / (H - 1));
            v = (c >= CIN + 2) ? sinf(3.14159265358979323846f * t) : t;
        }
        float r = v;
        r += __shfl_xor(r, 1); r += __shfl_xor(r, 2); r += __shfl_xor(r, 4);
        float cc = v;
        cc += __shfl_xor(cc, 8); cc += __shfl_xor(cc, 16); cc += __shfl_xor(cc, 32);
        float T = r;
        T += __shfl_xor(T, 8); T += __shfl_xor(T, 16); T += __shfl_xor(T, 32);
        float R0 = __shfl(r, 0), R7 = __shfl(r, 56);
        float C0 = __shfl(cc, 0), C7 = __shfl(cc, 7);
        float x00 = __shfl(v, 0), x07 = __shfl(v, 7);
        float x70 = __shfl(v, 56), x77 = __shfl(v, 63);
        if (lane < 9) {
            int i = lane / 3, j = lane % 3;
            float s = T;
            if (i == 0) s -= R7; else if (i == 2) s -= R0;
            if (j == 0) s -= C7; else if (j == 2) s -= C0;
            if (i == 0 && j == 0) s += x77;
            else if (i == 0 && j == 2) s += x70;
            else if (i == 2 && j == 0) s += x07;
            else if (i == 2 && j == 2) s += x00;
            Sw[c * 9 + lane] = s;
        }
    }
    __syncthreads();
    if (lane < 8) {
        const int o = lane;
        float acc = 0.f;
        for (int c = 0; c < C; ++c) {
            #pragma unroll
            for (int ij = 0; ij < 9; ++ij)
                acc += pw[(o * C + c) * 9 + ij] * Sw[c * 9 + ij];
        }
        Sw[C * 9 + o] = acc * (1.f / 64.f) + pb[o];
    }
    __syncthreads();
    if (lane == 0) {
        float lg[NE];
        float m = -1e30f;
        #pragma unroll
        for (int e = 0; e < NE; ++e) {
            float a = rb[e];
            #pragma unroll
            for (int o = 0; o < 8; ++o) a += Sw[C * 9 + o] * rw[e * 8 + o];
            lg[e] = a;
            m = fmaxf(m, a);
        }
        float ssum = 0.f;
        #pragma unroll
        for (int e = 0; e < NE; ++e) { lg[e] = __expf(lg[e] - m); ssum += lg[e]; }
        float inv = 1.f / ssum;
        #pragma unroll
        for (int e = 0; e < NE; ++e) scores[bp * NE + e] = lg[e] * inv;
    }
}

// ---------------- border: Xn border pixels = fin bias ----------------
__global__ __launch_bounds__(256) void border_kernel(float* __restrict__ Xn,
                                                     const float* __restrict__ fb,
                                                     int CO, int H, int W)
{
    const int Hout = H + 8, Wout = W + 8;
    const int nb = 16 * H + 64;
    const long total = (long)NB * CO * nb;
    for (long i = (long)blockIdx.x * blockDim.x + threadIdx.x; i < total;
         i += (long)gridDim.x * blockDim.x) {
        int j = (int)(i % nb); long t = i / nb; int o = (int)(t % CO); int b = (int)(t / CO);
        int y, x;
        if (j < 4 * Wout)       { y = j / Wout;             x = j % Wout; }
        else if (j < 8 * Wout)  { int j2 = j - 4 * Wout; y = H + 4 + j2 / Wout; x = j2 % Wout; }
        else                    { int j3 = j - 8 * Wout; y = 4 + j3 / 8;
                                  int c8 = j3 % 8; x = (c8 < 4) ? c8 : W + 4 + (c8 - 4); }
        Xn[(((size_t)b * CO + o) * Hout + y) * Wout + x] = fb[o];
    }
}

// ---------------- fused expert + fin, 2 patches per 512-thread block ----------------
// R21 = R18 (proven 789us config) + NONTEMPORAL X staging loads (via native vector
// type; HIP float4 class rejected by the builtin). Theory: L4 FETCH=118MB vs ~30MB
// compulsory => weights re-fetched from HBM because streaming X evicts them from the
// 4MB/XCD L2. X lines are read exactly once per kernel; nt keeps weights resident.
template<int CIN, int CINp, int CO>
__global__ __launch_bounds__(512, 2) void expert_fused_kernel(
    const float* __restrict__ X,
    const u16* __restrict__ Wm, const u16* __restrict__ Wp, const u16* __restrict__ fW,
    const float* __restrict__ eb, const float* __restrict__ fb,
    const float* __restrict__ scores, int BPtot,
    float* __restrict__ Xn, int H, int W, int nP)
{
    constexpr int M = NE * CO;
    constexpr int KSM = CINp / 32;
    constexpr int LOGK = (KSM == 4) ? 2 : (KSM == 2 ? 1 : 0);
    constexpr int NS = 9 * KSM;
    constexpr int SP = CINp + 8;
    constexpr int PIP = 72;
    constexpr int CP = CO + 8;
    constexpr bool FAT = (CO == 128);
    constexpr bool UNI = (CIN == 3);     // L1: unified K=64 GEMM only
    constexpr int NT = FAT ? 8 : 4;
    constexpr int PATW = 2 * 100 * SP;
    constexpr int POSW = 2 * 64 * PIP;
    constexpr int COMBW = 2 * 64 * CP;
    constexpr int SMW = (PATW + POSW > COMBW) ? (PATW + POSW) : COMBW;

    __shared__ __align__(16) u16 smem[SMW];
    __shared__ float pospix[2][4][64];
    __shared__ float xpix[2][3][64];   // UNI only
    __shared__ float gsh[8][NE];
    u16* pat = smem;
    u16* posim = smem + PATW;
    u16* comb = smem;              // aliases pat/posim; valid after the post-GEMM barrier

    const int P = nP * nP;
    const int bp0 = blockIdx.x * 2, bp1 = bp0 + 1;
    const int b0 = bp0 / P, pi0 = bp0 % P, py0 = pi0 / nP, px0 = pi0 % nP;
    const int b1 = bp1 / P, pi1 = bp1 % P, py1 = pi1 / nP, px1 = pi1 % nP;
    const int tid = threadIdx.x;
    const int Hout = H + 8, Wout = W + 8;

    // ---- phase A: zero pat (non-UNI), pospix, xpix (UNI), gate partial scan ----
    if constexpr (!UNI) {
        for (int i = tid; i < 100 * SP; i += 512) ((u32*)pat)[i] = 0;
    }
    {
        int g = tid >> 8, r = tid & 255, pc = r >> 6, p = r & 63;
        int gy = (g ? py1 : py0) * 8 + (p >> 3), gx = (g ? px1 : px0) * 8 + (p & 7);
        float t = (pc == 0 || pc == 2) ? gx * (1.f / (W - 1)) : gy * (1.f / (H - 1));
        pospix[g][pc][p] = (pc >= 2) ? sinf(3.14159265358979323846f * t) : t;
    }
    if constexpr (UNI) {
        for (int i = tid; i < 2 * 3 * 64; i += 512) {
            int g = i / 192, r = i % 192, c = r >> 6, p = r & 63;
            int bb = g ? b1 : b0, py = g ? py1 : py0, px = g ? px1 : px0;
            xpix[g][c][p] = __builtin_nontemporal_load(
                &X[(((size_t)bb * CIN + c) * H + py * 8 + (p >> 3)) * W + px * 8 + (p & 7)]);
        }
    }
    float gm[NE] = {-1e30f, -1e30f, -1e30f, -1e30f};
    for (int i = tid; i < BPtot; i += 512) {
        float4 sc = ((const float4*)scores)[i];
        gm[0] = fmaxf(gm[0], sc.x); gm[1] = fmaxf(gm[1], sc.y);
        gm[2] = fmaxf(gm[2], sc.z); gm[3] = fmaxf(gm[3], sc.w);
    }
    __syncthreads();

    // ---- phase B: fill pat (non-UNI), build posim, gate wave-reduce ----
    if constexpr (!UNI) {
        for (int i = tid; i < 2 * CIN * 16; i += 512) {
            int g = i / (CIN * 16), j = i % (CIN * 16);
            int c = j >> 4, q = j & 15, h = q >> 1, w4 = (q & 1) * 4;
            int bb = g ? b1 : b0, py = g ? py1 : py0, px = g ? px1 : px0;
            const f32x4 v = __builtin_nontemporal_load(
                (const f32x4*)&X[(((size_t)bb * CIN + c) * H + py * 8 + h) * W + px * 8 + w4]);
            int base = g * 100 * SP + c;
            pat[base + ((h + 1) * 10 + (w4 + 1)) * SP] = f16bits(v.x);
            pat[base + ((h + 1) * 10 + (w4 + 2)) * SP] = f16bits(v.y);
            pat[base + ((h + 1) * 10 + (w4 + 3)) * SP] = f16bits(v.z);
            pat[base + ((h + 1) * 10 + (w4 + 4)) * SP] = f16bits(v.w);
        }
    }
    for (int i = tid; i < 2 * 64 * 64; i += 512) {
        int g = i >> 12, r = i & 4095, pix = r >> 6, kp = r & 63;
        float v = 0.f;
        if constexpr (UNI) {
            if (kp < 27) {
                int c = kp / 9, ij = kp % 9;
                int hh = (pix >> 3) + ij / 3 - 1, ww = (pix & 7) + ij % 3 - 1;
                if (hh >= 0 && hh < 8 && ww >= 0 && ww < 8) v = xpix[g][c][hh * 8 + ww];
            } else if (kp < 63) {
                int q = kp - 27; int pc = q / 9, ij = q % 9;
                int hh = (pix >> 3) + ij / 3 - 1, ww = (pix & 7) + ij % 3 - 1;
                if (hh >= 0 && hh < 8 && ww >= 0 && ww < 8) v = pospix[g][pc][hh * 8 + ww];
            }
        } else {
            if (kp < 36) {
                int pc = kp / 9, ij = kp % 9;
                int hh = (pix >> 3) + ij / 3 - 1, ww = (pix & 7) + ij % 3 - 1;
                if (hh >= 0 && hh < 8 && ww >= 0 && ww < 8) v = pospix[g][pc][hh * 8 + ww];
            }
        }
        posim[g * 64 * PIP + pix * PIP + kp] = f16bits(v);
    }
    {
        const int lane = tid & 63, wvi = tid >> 6;
        #pragma unroll
        for (int e = 0; e < NE; ++e) {
            float v = gm[e];
            for (int o = 32; o; o >>= 1) v = fmaxf(v, __shfl_xor(v, o));
            gm[e] = v;
        }
        if (lane == 0) {
            #pragma unroll
            for (int e = 0; e < NE; ++e) gsh[wvi][e] = gm[e];
        }
    }
    __syncthreads();

    const int lane = tid & 63, wv = tid >> 6;
    const int colp = lane & 15, kg = lane >> 4;
    const int cot = FAT ? wv : (wv & 3);
    const int gO = FAT ? 0 : (wv >> 2);
    const int co0 = cot * 16;

    int prow[NT];
    #pragma unroll
    for (int nt = 0; nt < NT; ++nt) {
        int g = FAT ? (nt >> 2) : gO;
        int pix = (nt & 3) * 16 + colp;
        prow[nt] = g * 100 * SP + ((pix >> 3) * 10 + (pix & 7)) * SP;
    }
    int aoff[NE];
    #pragma unroll
    for (int e = 0; e < NE; ++e)
        aoff[e] = (e * CO + co0 + colp) * CINp + kg * 8;

    f32x4 acc[NE][NT];
    #pragma unroll
    for (int e = 0; e < NE; ++e)
        #pragma unroll
        for (int nt = 0; nt < NT; ++nt) acc[e][nt] = (f32x4){0.f, 0.f, 0.f, 0.f};

    f16x8 A0[NE], A1[NE];
    if constexpr (!UNI) {
        // ---- main GEMM: flattened steps s = ij*KSM + ks, depth-1 A-prefetch ----
        auto ldA = [&](int s, f16x8* A) {
            int ij = s >> LOGK, ks = s & (KSM - 1);
            const u16* Ws = Wm + (size_t)(ij * M) * CINp + ks * 32;
            #pragma unroll
            for (int e = 0; e < NE; ++e) A[e] = *(const f16x8*)(Ws + aoff[e]);
        };
        auto doStep = [&](int s, f16x8* A) {
            int ij = s >> LOGK, ks = s & (KSM - 1);
            int i3 = ij / 3;
            int tb = (i3 * 10 + (ij - 3 * i3)) * SP + ks * 32 + kg * 8;
            #pragma unroll
            for (int nt = 0; nt < NT; ++nt) {
                f16x8 Bv = *(const f16x8*)&pat[prow[nt] + tb];
                __builtin_amdgcn_s_setprio(1);
                #pragma unroll
                for (int e = 0; e < NE; ++e)
                    acc[e][nt] = __builtin_amdgcn_mfma_f32_16x16x32_f16(A[e], Bv, acc[e][nt], 0, 0, 0);
                __builtin_amdgcn_s_setprio(0);
            }
        };
        ldA(0, A0);
        int s = 0;
        for (; s + 1 < NS; s += 2) {
            ldA(s + 1, A1);
            doStep(s, A0);
            ldA((s + 2 < NS) ? s + 2 : s + 1, A0);
            doStep(s + 1, A1);
        }
        if (s < NS) doStep(s, A0);   // odd-NS tail
    }

    // ---- posim GEMM (K=64): pos-only for non-UNI, the ENTIRE conv for UNI ----
    #pragma unroll
    for (int ks = 0; ks < 2; ++ks) {
        #pragma unroll
        for (int e = 0; e < NE; ++e) {
            int ao = (e * CO + co0 + colp) * 64 + ks * 32 + kg * 8;
            A0[e] = *(const f16x8*)(Wp + ao);
        }
        #pragma unroll
        for (int nt = 0; nt < NT; ++nt) {
            int g = FAT ? (nt >> 2) : gO;
            int pix = (nt & 3) * 16 + colp;
            f16x8 Bv = *(const f16x8*)&posim[g * 64 * PIP + pix * PIP + ks * 32 + kg * 8];
            __builtin_amdgcn_s_setprio(1);
            #pragma unroll
            for (int e = 0; e < NE; ++e)
                acc[e][nt] = __builtin_amdgcn_mfma_f32_16x16x32_f16(A0[e], Bv, acc[e][nt], 0, 0, 0);
            __builtin_amdgcn_s_setprio(0);
        }
    }

    float sg0[NE], sg1[NE];
    #pragma unroll
    for (int e = 0; e < NE; ++e) {
        float mx = gsh[0][e];
        #pragma unroll
        for (int w8 = 1; w8 < 8; ++w8) mx = fmaxf(mx, gsh[w8][e]);
        float gv = (mx > THRESH) ? 1.f : 0.f;
        sg0[e] = scores[bp0 * NE + e] * gv;
        sg1[e] = scores[bp1 * NE + e] * gv;
    }
    float ebv[NE][4];
    #pragma unroll
    for (int e = 0; e < NE; ++e)
        #pragma unroll
        for (int r = 0; r < 4; ++r) ebv[e][r] = eb[e * CO + co0 + kg * 4 + r];

    __syncthreads();   // all pat/posim reads done; comb may now overwrite the region

    #pragma unroll
    for (int nt = 0; nt < NT; ++nt) {
        const int g = FAT ? (nt >> 2) : gO;
        int pix = (nt & 3) * 16 + colp;
        u16 hv[4];
        #pragma unroll
        for (int r = 0; r < 4; ++r) {
            float cv = 0.f;
            #pragma unroll
            for (int e = 0; e < NE; ++e) {
                float s2 = g ? sg1[e] : sg0[e];
                cv += s2 * fmaxf(acc[e][nt][r] + ebv[e][r], 0.f);
            }
            hv[r] = f16bits(cv);
        }
        uint2 q;
        q.x = (u32)hv[0] | ((u32)hv[1] << 16);
        q.y = (u32)hv[2] | ((u32)hv[3] << 16);
        *(uint2*)&comb[g * 64 * CP + pix * CP + co0 + kg * 4] = q;
    }
    __syncthreads();

    const int o0 = co0;
    f32x4 accF[NT];
    #pragma unroll
    for (int nt = 0; nt < NT; ++nt) accF[nt] = (f32x4){0.f, 0.f, 0.f, 0.f};
    #pragma unroll
    for (int ks = 0; ks < CO / 32; ++ks) {
        int ao = (o0 + colp) * CO + ks * 32 + kg * 8;
        f16x8 ah = *(const f16x8*)(fW + ao);
        __builtin_amdgcn_s_setprio(1);
        #pragma unroll
        for (int nt = 0; nt < NT; ++nt) {
            int g = FAT ? (nt >> 2) : gO;
            int pix = (nt & 3) * 16 + colp;
            f16x8 bv = *(const f16x8*)&comb[g * 64 * CP + pix * CP + ks * 32 + kg * 8];
            accF[nt] = __builtin_amdgcn_mfma_f32_16x16x32_f16(ah, bv, accF[nt], 0, 0, 0);
        }
        __builtin_amdgcn_s_setprio(0);
    }
    float fbv[4];
    #pragma unroll
    for (int r = 0; r < 4; ++r) fbv[r] = fb[o0 + kg * 4 + r];
    #pragma unroll
    for (int nt = 0; nt < NT; ++nt) {
        const int g = FAT ? (nt >> 2) : gO;
        int pix = (nt & 3) * 16 + colp;
        int bb = g ? b1 : b0, py = g ? py1 : py0, px = g ? px1 : px0;
        int gy = py * 8 + (pix >> 3) + 4, gx = px * 8 + (pix & 7) + 4;
        #pragma unroll
        for (int r = 0; r < 4; ++r) {
            int o = o0 + kg * 4 + r;
            Xn[(((size_t)bb * CO + o) * Hout + gy) * Wout + gx] = accF[nt][r] + fbv[r];
        }
    }
}

// ---------------- final linear: stage 1 — 4 batches per block, weights read once ----------------
__global__ __launch_bounds__(256) void linear_part_kernel(
    const float* __restrict__ Xf, const float* __restrict__ lw, float* __restrict__ part)
{
    const int feat = 128 * 96 * 96;
    const int CH = feat / LIN_NS;          // 18432
    const int s = blockIdx.x & (LIN_NS - 1);
    const int bg = blockIdx.x / LIN_NS;    // 0..3
    float acc[4][10];
    #pragma unroll
    for (int bb = 0; bb < 4; ++bb)
        #pragma unroll
        for (int o = 0; o < 10; ++o) acc[bb][o] = 0.f;
    const int n4 = CH / 4;                 // 4608
    for (int i = threadIdx.x; i < n4; i += 256) {
        float4 wv[10];
        #pragma unroll
        for (int o = 0; o < 10; ++o)
            wv[o] = *(const float4*)(lw + (size_t)o * feat + (size_t)s * CH + i * 4);
        #pragma unroll
        for (int bb = 0; bb < 4; ++bb) {
            float4 xv = *(const float4*)(Xf + (size_t)(bg * 4 + bb) * feat + (size_t)s * CH + i * 4);
            #pragma unroll
            for (int o = 0; o < 10; ++o)
                acc[bb][o] += xv.x * wv[o].x + xv.y * wv[o].y + xv.z * wv[o].z + xv.w * wv[o].w;
        }
    }
    #pragma unroll
    for (int bb = 0; bb < 4; ++bb)
        #pragma unroll
        for (int o = 0; o < 10; ++o)
            for (int m = 32; m; m >>= 1) acc[bb][o] += __shfl_xor(acc[bb][o], m);
    __shared__ float sm[4][40];
    int wvi = threadIdx.x >> 6, lane = threadIdx.x & 63;
    if (lane == 0) {
        #pragma unroll
        for (int bb = 0; bb < 4; ++bb)
            #pragma unroll
            for (int o = 0; o < 10; ++o) sm[wvi][bb * 10 + o] = acc[bb][o];
    }
    __syncthreads();
    int t = threadIdx.x;
    if (t < 40) {
        float a = sm[0][t] + sm[1][t] + sm[2][t] + sm[3][t];
        int bb = t / 10, o = t % 10;
        int b = bg * 4 + bb;
        part[(b * LIN_NS + s) * 10 + o] = a;
    }
}

// ---------------- final linear: stage 2 — reduce splits + bias (deterministic) ----------------
__global__ __launch_bounds__(256) void linear_reduce_kernel(
    const float* __restrict__ part, const float* __restrict__ lb, float* __restrict__ out)
{
    int i = threadIdx.x;
    if (i < 160) {
        int b = i / 10, o = i % 10;
        float a = lb[o];
        for (int s = 0; s < LIN_NS; ++s) a += part[(b * LIN_NS + s) * 10 + o];
        out[i] = a;
    }
}

// ---------------- host driver ----------------
template<int CIN, int CINp, int CO>
static void run_layer(const float* Xin, int H, int nP, const float* const* Lw,
                      const float* rw, const float* rb,
                      const u16* Wm, const u16* Wp, const u16* fW,
                      float* scores, float* Xn, hipStream_t stream)
{
    const int W = H;
    const int BP = NB * nP * nP;
    const float* pw = Lw[0]; const float* pb = Lw[1];
    const float* ebias = Lw[3];
    const float* fb = Lw[5];

    router_kernel<CIN, CIN + 4><<<BP / 4, 256, 0, stream>>>(Xin, pw, pb, rw, rb, scores, H, W, nP);
    border_kernel<<<2048, 256, 0, stream>>>(Xn, fb, CO, H, W);
    expert_fused_kernel<CIN, CINp, CO><<<BP / 2, 512, 0, stream>>>(
        Xin, Wm, Wp, fW, ebias, fb, scores, BP, Xn, H, W, nP);
}

extern "C" void kernel_launch(void* const* d_in, const int* in_sizes, int n_in,
                              void* d_out, int out_size, void* d_ws, size_t ws_size,
                              hipStream_t stream)
{
    const float* X0 = (const float*)d_in[0];
    const float* L[4][6];
    for (int l = 0; l < 4; ++l)
        for (int k = 0; k < 6; ++k) L[l][k] = (const float*)d_in[1 + l * 6 + k];
    const float* rw = (const float*)d_in[25];
    const float* rb = (const float*)d_in[26];
    const float* lw = (const float*)d_in[27];
    const float* lb = (const float*)d_in[28];

    // workspace (~141.5 MB): ping-pong X buffers + per-layer fp16 weights + linear partials
    char* ws = (char*)d_ws;
    const size_t XA_B = 63438848;    // 16*128*88*88*4 (L3 out, max for A)
    const size_t XB_B = 75497472;    // 16*128*96*96*4 (L4 out, max for B)
    float* XA = (float*)(ws);
    float* XB = (float*)(ws + XA_B);
    char* wp = ws + XA_B + XB_B;
    const int cfg_CO[4]   = {64, 64, 128, 128};
    const int cfg_CINp[4] = {32, 64, 64, 128};
    u16 *Wm[4], *Wp[4], *fW[4];
    for (int l = 0; l < 4; ++l) {
        int M = NE * cfg_CO[l];
        Wm[l] = (u16*)wp;            wp += (size_t)9 * M * cfg_CINp[l] * 2;
        Wp[l] = (u16*)wp;            wp += (size_t)M * 64 * 2;
        fW[l] = (u16*)wp;            wp += (size_t)cfg_CO[l] * cfg_CO[l] * 2;
    }
    float* scores = (float*)wp;
    float* lpart = scores + 1936 * 4;  // 16*LIN_NS*10 floats

    // all repacks upfront (off the inter-layer critical path)
    const int cfg_CIN[4] = {3, 64, 64, 128};
    for (int l = 0; l < 4; ++l)
        repack_all_kernel<<<512, 256, 0, stream>>>(L[l][2], L[l][4], Wm[l], Wp[l], fW[l],
                                                   cfg_CO[l], cfg_CIN[l], cfg_CINp[l], cfg_CIN[l] + 4);

    // layer l: X (NB,CIN,H,H) -> Xn (NB,CO,H+8,H+8), ping-pong A/B
    run_layer<3,   32,  64>(X0, 64,  8, L[0], rw, rb, Wm[0], Wp[0], fW[0], scores, XA, stream);
    run_layer<64,  64,  64>(XA, 72,  9, L[1], rw, rb, Wm[1], Wp[1], fW[1], scores, XB, stream);
    run_layer<64,  64, 128>(XB, 80, 10, L[2], rw, rb, Wm[2], Wp[2], fW[2], scores, XA, stream);
    run_layer<128, 128, 128>(XA, 88, 11, L[3], rw, rb, Wm[3], Wp[3], fW[3], scores, XB, stream);

    linear_part_kernel<<<LIN_NS * (NB / 4), 256, 0, stream>>>(XB, lw, lpart);
    linear_reduce_kernel<<<1, 256, 0, stream>>>(lpart, lb, (float*)d_out);
}

// Round 22
// 786.222 us; speedup vs baseline: 1.2321x; 1.0324x over previous
//
#include <hip/hip_runtime.h>
#include <math.h>

#define NB 16
#define NE 4
#define THRESH 0.2f
#define LIN_NS 64

typedef __attribute__((ext_vector_type(8))) _Float16 f16x8;
typedef __attribute__((ext_vector_type(4))) float f32x4;
typedef unsigned short u16;
typedef unsigned int u32;

__device__ inline u16 f16bits(float v) { _Float16 h = (_Float16)v; return __builtin_bit_cast(u16, h); }

// ---------------- repack: expert weights (main+pos) and fin weights to single fp16 ----------------
// Wm: [ij][m=e*CO+co][CINp]   Wp: [m][64]   fW: [o][CO]
// CIN==3 (L1): Wp holds the UNIFIED K=64 weights (27 main + 36 pos).
__global__ void repack_all_kernel(const float* __restrict__ ew, const float* __restrict__ fw,
    u16* __restrict__ Wm, u16* __restrict__ Wp, u16* __restrict__ fW,
    int CO, int CIN, int CINp, int C) {
    const int M = NE * CO;
    const int n1 = 9 * M * CINp, n2 = M * 64, n3 = CO * CO;
    const int n = n1 + n2 + n3;
    for (int i = blockIdx.x * blockDim.x + threadIdx.x; i < n; i += gridDim.x * blockDim.x) {
        if (i < n1) {
            int k = i % CINp; int t = i / CINp; int m = t % M; int ij = t / M;
            float v = (k < CIN) ? ew[(m * C + k) * 9 + ij] : 0.f;
            Wm[i] = f16bits(v);
        } else if (i < n1 + n2) {
            int j = i - n1; int kp = j & 63; int m = j >> 6;
            float v = 0.f;
            if (CIN == 3) {
                if (kp < 27)      { int c = kp / 9,  ij = kp % 9;  v = ew[(m * C + c) * 9 + ij]; }
                else if (kp < 63) { int q = kp - 27; int pc = q / 9, ij = q % 9; v = ew[(m * C + 3 + pc) * 9 + ij]; }
            } else {
                if (kp < 36) { int pc = kp / 9, ij = kp % 9; v = ew[(m * C + CIN + pc) * 9 + ij]; }
            }
            Wp[j] = f16bits(v);
        } else {
            int j = i - n1 - n2;
            fW[j] = f16bits(fw[j]);
        }
    }
}

// ---------------- router: pooled conv -> softmax scores (verified; NO atomics) ----------------
template<int CIN, int C>
__global__ __launch_bounds__(256) void router_kernel(
    const float* __restrict__ X, const float* __restrict__ pw, const float* __restrict__ pb,
    const float* __restrict__ rw, const float* __restrict__ rb,
    float* __restrict__ scores, int H, int W, int nP)
{
    __shared__ float S[4][C * 9 + 8];
    const int wv = threadIdx.x >> 6;
    const int lane = threadIdx.x & 63;
    const int bp = blockIdx.x * 4 + wv;
    const int P = nP * nP;
    const int b = bp / P, pi = bp % P;
    const int py = pi / nP, px = pi % nP;
    const int h = lane >> 3, w = lane & 7;
    const int gy = py * 8 + h, gx = px * 8 + w;
    float* Sw = S[wv];
    for (int c = 0; c < C; ++c) {
        float v;
        if (c < CIN) {
            v = X[(((size_t)b * CIN + c) * H + gy) * W + gx];
        } else {
            float t = (c == CIN || c == CIN + 2) ? gx * (1.f / (W - 1)) : gy * (1.f / (H - 1));
            v = (c >= CIN + 2) ? sinf(3.14159265358979323846f * t) : t;
        }
        float r = v;
        r += __shfl_xor(r, 1); r += __shfl_xor(r, 2); r += __shfl_xor(r, 4);
        float cc = v;
        cc += __shfl_xor(cc, 8); cc += __shfl_xor(cc, 16); cc += __shfl_xor(cc, 32);
        float T = r;
        T += __shfl_xor(T, 8); T += __shfl_xor(T, 16); T += __shfl_xor(T, 32);
        float R0 = __shfl(r, 0), R7 = __shfl(r, 56);
        float C0 = __shfl(cc, 0), C7 = __shfl(cc, 7);
        float x00 = __shfl(v, 0), x07 = __shfl(v, 7);
        float x70 = __shfl(v, 56), x77 = __shfl(v, 63);
        if (lane < 9) {
            int i = lane / 3, j = lane % 3;
            float s = T;
            if (i == 0) s -= R7; else if (i == 2) s -= R0;
            if (j == 0) s -= C7; else if (j == 2) s -= C0;
            if (i == 0 && j == 0) s += x77;
            else if (i == 0 && j == 2) s += x70;
            else if (i == 2 && j == 0) s += x07;
            else if (i == 2 && j == 2) s += x00;
            Sw[c * 9 + lane] = s;
        }
    }
    __syncthreads();
    if (lane < 8) {
        const int o = lane;
        float acc = 0.f;
        for (int c = 0; c < C; ++c) {
            #pragma unroll
            for (int ij = 0; ij < 9; ++ij)
                acc += pw[(o * C + c) * 9 + ij] * Sw[c * 9 + ij];
        }
        Sw[C * 9 + o] = acc * (1.f / 64.f) + pb[o];
    }
    __syncthreads();
    if (lane == 0) {
        float lg[NE];
        float m = -1e30f;
        #pragma unroll
        for (int e = 0; e < NE; ++e) {
            float a = rb[e];
            #pragma unroll
            for (int o = 0; o < 8; ++o) a += Sw[C * 9 + o] * rw[e * 8 + o];
            lg[e] = a;
            m = fmaxf(m, a);
        }
        float ssum = 0.f;
        #pragma unroll
        for (int e = 0; e < NE; ++e) { lg[e] = __expf(lg[e] - m); ssum += lg[e]; }
        float inv = 1.f / ssum;
        #pragma unroll
        for (int e = 0; e < NE; ++e) scores[bp * NE + e] = lg[e] * inv;
    }
}

// ---------------- border: Xn border pixels = fin bias ----------------
__global__ __launch_bounds__(256) void border_kernel(float* __restrict__ Xn,
                                                     const float* __restrict__ fb,
                                                     int CO, int H, int W)
{
    const int Hout = H + 8, Wout = W + 8;
    const int nb = 16 * H + 64;
    const long total = (long)NB * CO * nb;
    for (long i = (long)blockIdx.x * blockDim.x + threadIdx.x; i < total;
         i += (long)gridDim.x * blockDim.x) {
        int j = (int)(i % nb); long t = i / nb; int o = (int)(t % CO); int b = (int)(t / CO);
        int y, x;
        if (j < 4 * Wout)       { y = j / Wout;             x = j % Wout; }
        else if (j < 8 * Wout)  { int j2 = j - 4 * Wout; y = H + 4 + j2 / Wout; x = j2 % Wout; }
        else                    { int j3 = j - 8 * Wout; y = 4 + j3 / 8;
                                  int c8 = j3 % 8; x = (c8 < 4) ? c8 : W + 4 + (c8 - 4); }
        Xn[(((size_t)b * CO + o) * Hout + y) * Wout + x] = fb[o];
    }
}

// ---------------- fused expert + fin, 2 patches per 512-thread block ----------------
// R22 = R18 exact (best measured 789us): R17 pipelined A-stream core, folded gate,
// UNI L1, (512,2), comb aliases pat/posim. R21's nontemporal X loads REVERTED
// (refuted: FETCH rose 118->134MB, perf -3%; HBM time ~42us of 265us is not the
// binder — the expert is in-wave latency-bound at the 248/256-reg ceiling).
template<int CIN, int CINp, int CO>
__global__ __launch_bounds__(512, 2) void expert_fused_kernel(
    const float* __restrict__ X,
    const u16* __restrict__ Wm, const u16* __restrict__ Wp, const u16* __restrict__ fW,
    const float* __restrict__ eb, const float* __restrict__ fb,
    const float* __restrict__ scores, int BPtot,
    float* __restrict__ Xn, int H, int W, int nP)
{
    constexpr int M = NE * CO;
    constexpr int KSM = CINp / 32;
    constexpr int LOGK = (KSM == 4) ? 2 : (KSM == 2 ? 1 : 0);
    constexpr int NS = 9 * KSM;
    constexpr int SP = CINp + 8;
    constexpr int PIP = 72;
    constexpr int CP = CO + 8;
    constexpr bool FAT = (CO == 128);
    constexpr bool UNI = (CIN == 3);     // L1: unified K=64 GEMM only
    constexpr int NT = FAT ? 8 : 4;
    constexpr int PATW = 2 * 100 * SP;
    constexpr int POSW = 2 * 64 * PIP;
    constexpr int COMBW = 2 * 64 * CP;
    constexpr int SMW = (PATW + POSW > COMBW) ? (PATW + POSW) : COMBW;

    __shared__ __align__(16) u16 smem[SMW];
    __shared__ float pospix[2][4][64];
    __shared__ float xpix[2][3][64];   // UNI only
    __shared__ float gsh[8][NE];
    u16* pat = smem;
    u16* posim = smem + PATW;
    u16* comb = smem;              // aliases pat/posim; valid after the post-GEMM barrier

    const int P = nP * nP;
    const int bp0 = blockIdx.x * 2, bp1 = bp0 + 1;
    const int b0 = bp0 / P, pi0 = bp0 % P, py0 = pi0 / nP, px0 = pi0 % nP;
    const int b1 = bp1 / P, pi1 = bp1 % P, py1 = pi1 / nP, px1 = pi1 % nP;
    const int tid = threadIdx.x;
    const int Hout = H + 8, Wout = W + 8;

    // ---- phase A: zero pat (non-UNI), pospix, xpix (UNI), gate partial scan ----
    if constexpr (!UNI) {
        for (int i = tid; i < 100 * SP; i += 512) ((u32*)pat)[i] = 0;
    }
    {
        int g = tid >> 8, r = tid & 255, pc = r >> 6, p = r & 63;
        int gy = (g ? py1 : py0) * 8 + (p >> 3), gx = (g ? px1 : px0) * 8 + (p & 7);
        float t = (pc == 0 || pc == 2) ? gx * (1.f / (W - 1)) : gy * (1.f / (H - 1));
        pospix[g][pc][p] = (pc >= 2) ? sinf(3.14159265358979323846f * t) : t;
    }
    if constexpr (UNI) {
        for (int i = tid; i < 2 * 3 * 64; i += 512) {
            int g = i / 192, r = i % 192, c = r >> 6, p = r & 63;
            int bb = g ? b1 : b0, py = g ? py1 : py0, px = g ? px1 : px0;
            xpix[g][c][p] = X[(((size_t)bb * CIN + c) * H + py * 8 + (p >> 3)) * W + px * 8 + (p & 7)];
        }
    }
    float gm[NE] = {-1e30f, -1e30f, -1e30f, -1e30f};
    for (int i = tid; i < BPtot; i += 512) {
        float4 sc = ((const float4*)scores)[i];
        gm[0] = fmaxf(gm[0], sc.x); gm[1] = fmaxf(gm[1], sc.y);
        gm[2] = fmaxf(gm[2], sc.z); gm[3] = fmaxf(gm[3], sc.w);
    }
    __syncthreads();

    // ---- phase B: fill pat (non-UNI), build posim, gate wave-reduce ----
    if constexpr (!UNI) {
        for (int i = tid; i < 2 * CIN * 16; i += 512) {
            int g = i / (CIN * 16), j = i % (CIN * 16);
            int c = j >> 4, q = j & 15, h = q >> 1, w4 = (q & 1) * 4;
            int bb = g ? b1 : b0, py = g ? py1 : py0, px = g ? px1 : px0;
            const float4 v = *(const float4*)&X[(((size_t)bb * CIN + c) * H + py * 8 + h) * W + px * 8 + w4];
            int base = g * 100 * SP + c;
            pat[base + ((h + 1) * 10 + (w4 + 1)) * SP] = f16bits(v.x);
            pat[base + ((h + 1) * 10 + (w4 + 2)) * SP] = f16bits(v.y);
            pat[base + ((h + 1) * 10 + (w4 + 3)) * SP] = f16bits(v.z);
            pat[base + ((h + 1) * 10 + (w4 + 4)) * SP] = f16bits(v.w);
        }
    }
    for (int i = tid; i < 2 * 64 * 64; i += 512) {
        int g = i >> 12, r = i & 4095, pix = r >> 6, kp = r & 63;
        float v = 0.f;
        if constexpr (UNI) {
            if (kp < 27) {
                int c = kp / 9, ij = kp % 9;
                int hh = (pix >> 3) + ij / 3 - 1, ww = (pix & 7) + ij % 3 - 1;
                if (hh >= 0 && hh < 8 && ww >= 0 && ww < 8) v = xpix[g][c][hh * 8 + ww];
            } else if (kp < 63) {
                int q = kp - 27; int pc = q / 9, ij = q % 9;
                int hh = (pix >> 3) + ij / 3 - 1, ww = (pix & 7) + ij % 3 - 1;
                if (hh >= 0 && hh < 8 && ww >= 0 && ww < 8) v = pospix[g][pc][hh * 8 + ww];
            }
        } else {
            if (kp < 36) {
                int pc = kp / 9, ij = kp % 9;
                int hh = (pix >> 3) + ij / 3 - 1, ww = (pix & 7) + ij % 3 - 1;
                if (hh >= 0 && hh < 8 && ww >= 0 && ww < 8) v = pospix[g][pc][hh * 8 + ww];
            }
        }
        posim[g * 64 * PIP + pix * PIP + kp] = f16bits(v);
    }
    {
        const int lane = tid & 63, wvi = tid >> 6;
        #pragma unroll
        for (int e = 0; e < NE; ++e) {
            float v = gm[e];
            for (int o = 32; o; o >>= 1) v = fmaxf(v, __shfl_xor(v, o));
            gm[e] = v;
        }
        if (lane == 0) {
            #pragma unroll
            for (int e = 0; e < NE; ++e) gsh[wvi][e] = gm[e];
        }
    }
    __syncthreads();

    const int lane = tid & 63, wv = tid >> 6;
    const int colp = lane & 15, kg = lane >> 4;
    const int cot = FAT ? wv : (wv & 3);
    const int gO = FAT ? 0 : (wv >> 2);
    const int co0 = cot * 16;

    int prow[NT];
    #pragma unroll
    for (int nt = 0; nt < NT; ++nt) {
        int g = FAT ? (nt >> 2) : gO;
        int pix = (nt & 3) * 16 + colp;
        prow[nt] = g * 100 * SP + ((pix >> 3) * 10 + (pix & 7)) * SP;
    }
    int aoff[NE];
    #pragma unroll
    for (int e = 0; e < NE; ++e)
        aoff[e] = (e * CO + co0 + colp) * CINp + kg * 8;

    f32x4 acc[NE][NT];
    #pragma unroll
    for (int e = 0; e < NE; ++e)
        #pragma unroll
        for (int nt = 0; nt < NT; ++nt) acc[e][nt] = (f32x4){0.f, 0.f, 0.f, 0.f};

    f16x8 A0[NE], A1[NE];
    if constexpr (!UNI) {
        // ---- main GEMM: flattened steps s = ij*KSM + ks, depth-1 A-prefetch ----
        auto ldA = [&](int s, f16x8* A) {
            int ij = s >> LOGK, ks = s & (KSM - 1);
            const u16* Ws = Wm + (size_t)(ij * M) * CINp + ks * 32;
            #pragma unroll
            for (int e = 0; e < NE; ++e) A[e] = *(const f16x8*)(Ws + aoff[e]);
        };
        auto doStep = [&](int s, f16x8* A) {
            int ij = s >> LOGK, ks = s & (KSM - 1);
            int i3 = ij / 3;
            int tb = (i3 * 10 + (ij - 3 * i3)) * SP + ks * 32 + kg * 8;
            #pragma unroll
            for (int nt = 0; nt < NT; ++nt) {
                f16x8 Bv = *(const f16x8*)&pat[prow[nt] + tb];
                __builtin_amdgcn_s_setprio(1);
                #pragma unroll
                for (int e = 0; e < NE; ++e)
                    acc[e][nt] = __builtin_amdgcn_mfma_f32_16x16x32_f16(A[e], Bv, acc[e][nt], 0, 0, 0);
                __builtin_amdgcn_s_setprio(0);
            }
        };
        ldA(0, A0);
        int s = 0;
        for (; s + 1 < NS; s += 2) {
            ldA(s + 1, A1);
            doStep(s, A0);
            ldA((s + 2 < NS) ? s + 2 : s + 1, A0);
            doStep(s + 1, A1);
        }
        if (s < NS) doStep(s, A0);   // odd-NS tail
    }

    // ---- posim GEMM (K=64): pos-only for non-UNI, the ENTIRE conv for UNI ----
    #pragma unroll
    for (int ks = 0; ks < 2; ++ks) {
        #pragma unroll
        for (int e = 0; e < NE; ++e) {
            int ao = (e * CO + co0 + colp) * 64 + ks * 32 + kg * 8;
            A0[e] = *(const f16x8*)(Wp + ao);
        }
        #pragma unroll
        for (int nt = 0; nt < NT; ++nt) {
            int g = FAT ? (nt >> 2) : gO;
            int pix = (nt & 3) * 16 + colp;
            f16x8 Bv = *(const f16x8*)&posim[g * 64 * PIP + pix * PIP + ks * 32 + kg * 8];
            __builtin_amdgcn_s_setprio(1);
            #pragma unroll
            for (int e = 0; e < NE; ++e)
                acc[e][nt] = __builtin_amdgcn_mfma_f32_16x16x32_f16(A0[e], Bv, acc[e][nt], 0, 0, 0);
            __builtin_amdgcn_s_setprio(0);
        }
    }

    float sg0[NE], sg1[NE];
    #pragma unroll
    for (int e = 0; e < NE; ++e) {
        float mx = gsh[0][e];
        #pragma unroll
        for (int w8 = 1; w8 < 8; ++w8) mx = fmaxf(mx, gsh[w8][e]);
        float gv = (mx > THRESH) ? 1.f : 0.f;
        sg0[e] = scores[bp0 * NE + e] * gv;
        sg1[e] = scores[bp1 * NE + e] * gv;
    }
    float ebv[NE][4];
    #pragma unroll
    for (int e = 0; e < NE; ++e)
        #pragma unroll
        for (int r = 0; r < 4; ++r) ebv[e][r] = eb[e * CO + co0 + kg * 4 + r];

    __syncthreads();   // all pat/posim reads done; comb may now overwrite the region

    #pragma unroll
    for (int nt = 0; nt < NT; ++nt) {
        const int g = FAT ? (nt >> 2) : gO;
        int pix = (nt & 3) * 16 + colp;
        u16 hv[4];
        #pragma unroll
        for (int r = 0; r < 4; ++r) {
            float cv = 0.f;
            #pragma unroll
            for (int e = 0; e < NE; ++e) {
                float s2 = g ? sg1[e] : sg0[e];
                cv += s2 * fmaxf(acc[e][nt][r] + ebv[e][r], 0.f);
            }
            hv[r] = f16bits(cv);
        }
        uint2 q;
        q.x = (u32)hv[0] | ((u32)hv[1] << 16);
        q.y = (u32)hv[2] | ((u32)hv[3] << 16);
        *(uint2*)&comb[g * 64 * CP + pix * CP + co0 + kg * 4] = q;
    }
    __syncthreads();

    const int o0 = co0;
    f32x4 accF[NT];
    #pragma unroll
    for (int nt = 0; nt < NT; ++nt) accF[nt] = (f32x4){0.f, 0.f, 0.f, 0.f};
    #pragma unroll
    for (int ks = 0; ks < CO / 32; ++ks) {
        int ao = (o0 + colp) * CO + ks * 32 + kg * 8;
        f16x8 ah = *(const f16x8*)(fW + ao);
        __builtin_amdgcn_s_setprio(1);
        #pragma unroll
        for (int nt = 0; nt < NT; ++nt) {
            int g = FAT ? (nt >> 2) : gO;
            int pix = (nt & 3) * 16 + colp;
            f16x8 bv = *(const f16x8*)&comb[g * 64 * CP + pix * CP + ks * 32 + kg * 8];
            accF[nt] = __builtin_amdgcn_mfma_f32_16x16x32_f16(ah, bv, accF[nt], 0, 0, 0);
        }
        __builtin_amdgcn_s_setprio(0);
    }
    float fbv[4];
    #pragma unroll
    for (int r = 0; r < 4; ++r) fbv[r] = fb[o0 + kg * 4 + r];
    #pragma unroll
    for (int nt = 0; nt < NT; ++nt) {
        const int g = FAT ? (nt >> 2) : gO;
        int pix = (nt & 3) * 16 + colp;
        int bb = g ? b1 : b0, py = g ? py1 : py0, px = g ? px1 : px0;
        int gy = py * 8 + (pix >> 3) + 4, gx = px * 8 + (pix & 7) + 4;
        #pragma unroll
        for (int r = 0; r < 4; ++r) {
            int o = o0 + kg * 4 + r;
            Xn[(((size_t)bb * CO + o) * Hout + gy) * Wout + gx] = accF[nt][r] + fbv[r];
        }
    }
}

// ---------------- final linear: stage 1 — 4 batches per block, weights read once ----------------
__global__ __launch_bounds__(256) void linear_part_kernel(
    const float* __restrict__ Xf, const float* __restrict__ lw, float* __restrict__ part)
{
    const int feat = 128 * 96 * 96;
    const int CH = feat / LIN_NS;          // 18432
    const int s = blockIdx.x & (LIN_NS - 1);
    const int bg = blockIdx.x / LIN_NS;    // 0..3
    float acc[4][10];
    #pragma unroll
    for (int bb = 0; bb < 4; ++bb)
        #pragma unroll
        for (int o = 0; o < 10; ++o) acc[bb][o] = 0.f;
    const int n4 = CH / 4;                 // 4608
    for (int i = threadIdx.x; i < n4; i += 256) {
        float4 wv[10];
        #pragma unroll
        for (int o = 0; o < 10; ++o)
            wv[o] = *(const float4*)(lw + (size_t)o * feat + (size_t)s * CH + i * 4);
        #pragma unroll
        for (int bb = 0; bb < 4; ++bb) {
            float4 xv = *(const float4*)(Xf + (size_t)(bg * 4 + bb) * feat + (size_t)s * CH + i * 4);
            #pragma unroll
            for (int o = 0; o < 10; ++o)
                acc[bb][o] += xv.x * wv[o].x + xv.y * wv[o].y + xv.z * wv[o].z + xv.w * wv[o].w;
        }
    }
    #pragma unroll
    for (int bb = 0; bb < 4; ++bb)
        #pragma unroll
        for (int o = 0; o < 10; ++o)
            for (int m = 32; m; m >>= 1) acc[bb][o] += __shfl_xor(acc[bb][o], m);
    __shared__ float sm[4][40];
    int wvi = threadIdx.x >> 6, lane = threadIdx.x & 63;
    if (lane == 0) {
        #pragma unroll
        for (int bb = 0; bb < 4; ++bb)
            #pragma unroll
            for (int o = 0; o < 10; ++o) sm[wvi][bb * 10 + o] = acc[bb][o];
    }
    __syncthreads();
    int t = threadIdx.x;
    if (t < 40) {
        float a = sm[0][t] + sm[1][t] + sm[2][t] + sm[3][t];
        int bb = t / 10, o = t % 10;
        int b = bg * 4 + bb;
        part[(b * LIN_NS + s) * 10 + o] = a;
    }
}

// ---------------- final linear: stage 2 — reduce splits + bias (deterministic) ----------------
__global__ __launch_bounds__(256) void linear_reduce_kernel(
    const float* __restrict__ part, const float* __restrict__ lb, float* __restrict__ out)
{
    int i = threadIdx.x;
    if (i < 160) {
        int b = i / 10, o = i % 10;
        float a = lb[o];
        for (int s = 0; s < LIN_NS; ++s) a += part[(b * LIN_NS + s) * 10 + o];
        out[i] = a;
    }
}

// ---------------- host driver ----------------
template<int CIN, int CINp, int CO>
static void run_layer(const float* Xin, int H, int nP, const float* const* Lw,
                      const float* rw, const float* rb,
                      const u16* Wm, const u16* Wp, const u16* fW,
                      float* scores, float* Xn, hipStream_t stream)
{
    const int W = H;
    const int BP = NB * nP * nP;
    const float* pw = Lw[0]; const float* pb = Lw[1];
    const float* ebias = Lw[3];
    const float* fb = Lw[5];

    router_kernel<CIN, CIN + 4><<<BP / 4, 256, 0, stream>>>(Xin, pw, pb, rw, rb, scores, H, W, nP);
    border_kernel<<<2048, 256, 0, stream>>>(Xn, fb, CO, H, W);
    expert_fused_kernel<CIN, CINp, CO><<<BP / 2, 512, 0, stream>>>(
        Xin, Wm, Wp, fW, ebias, fb, scores, BP, Xn, H, W, nP);
}

extern "C" void kernel_launch(void* const* d_in, const int* in_sizes, int n_in,
                              void* d_out, int out_size, void* d_ws, size_t ws_size,
                              hipStream_t stream)
{
    const float* X0 = (const float*)d_in[0];
    const float* L[4][6];
    for (int l = 0; l < 4; ++l)
        for (int k = 0; k < 6; ++k) L[l][k] = (const float*)d_in[1 + l * 6 + k];
    const float* rw = (const float*)d_in[25];
    const float* rb = (const float*)d_in[26];
    const float* lw = (const float*)d_in[27];
    const float* lb = (const float*)d_in[28];

    // workspace (~141.5 MB): ping-pong X buffers + per-layer fp16 weights + linear partials
    char* ws = (char*)d_ws;
    const size_t XA_B = 63438848;    // 16*128*88*88*4 (L3 out, max for A)
    const size_t XB_B = 75497472;    // 16*128*96*96*4 (L4 out, max for B)
    float* XA = (float*)(ws);
    float* XB = (float*)(ws + XA_B);
    char* wp = ws + XA_B + XB_B;
    const int cfg_CO[4]   = {64, 64, 128, 128};
    const int cfg_CINp[4] = {32, 64, 64, 128};
    u16 *Wm[4], *Wp[4], *fW[4];
    for (int l = 0; l < 4; ++l) {
        int M = NE * cfg_CO[l];
        Wm[l] = (u16*)wp;            wp += (size_t)9 * M * cfg_CINp[l] * 2;
        Wp[l] = (u16*)wp;            wp += (size_t)M * 64 * 2;
        fW[l] = (u16*)wp;            wp += (size_t)cfg_CO[l] * cfg_CO[l] * 2;
    }
    float* scores = (float*)wp;
    float* lpart = scores + 1936 * 4;  // 16*LIN_NS*10 floats

    // all repacks upfront (off the inter-layer critical path)
    const int cfg_CIN[4] = {3, 64, 64, 128};
    for (int l = 0; l < 4; ++l)
        repack_all_kernel<<<512, 256, 0, stream>>>(L[l][2], L[l][4], Wm[l], Wp[l], fW[l],
                                                   cfg_CO[l], cfg_CIN[l], cfg_CINp[l], cfg_CIN[l] + 4);

    // layer l: X (NB,CIN,H,H) -> Xn (NB,CO,H+8,H+8), ping-pong A/B
    run_layer<3,   32,  64>(X0, 64,  8, L[0], rw, rb, Wm[0], Wp[0], fW[0], scores, XA, stream);
    run_layer<64,  64,  64>(XA, 72,  9, L[1], rw, rb, Wm[1], Wp[1], fW[1], scores, XB, stream);
    run_layer<64,  64, 128>(XB, 80, 10, L[2], rw, rb, Wm[2], Wp[2], fW[2], scores, XA, stream);
    run_layer<128, 128, 128>(XA, 88, 11, L[3], rw, rb, Wm[3], Wp[3], fW[3], scores, XB, stream);

    linear_part_kernel<<<LIN_NS * (NB / 4), 256, 0, stream>>>(XB, lw, lpart);
    linear_reduce_kernel<<<1, 256, 0, stream>>>(lpart, lb, (float*)d_out);
}